// Round 3
// baseline (448.229 us; speedup 1.0000x reference)
//
#include <hip/hip_runtime.h>
#include <hip/hip_bf16.h>
#include <stdint.h>

typedef unsigned short u16;
typedef __attribute__((ext_vector_type(8))) __bf16 bf16x8;
typedef __attribute__((ext_vector_type(4))) float floatx4;
typedef __attribute__((ext_vector_type(8))) unsigned short us8;
typedef __attribute__((ext_vector_type(4))) unsigned short us4;

#define TT 4096
#define BB 4
#define DM 1024
#define ROWS (TT * BB)      // 16384 flattened (t,b) rows
#define CHUNK 128           // timesteps per chunk
#define CR (CHUNK * BB)     // 512 rows per chunk
#define NC (TT / CHUNK)     // 32 chunks
#define MB (1024l * 1024l)

__device__ __forceinline__ float b2f(u16 x) {
  union { unsigned int u; float f; } v; v.u = ((unsigned int)x) << 16; return v.f;
}
__device__ __forceinline__ u16 f2b(float f) {
  union { float f; unsigned int u; } v; v.f = f;
  unsigned int r = v.u + 0x7fffu + ((v.u >> 16) & 1u);   // RNE
  return (u16)(r >> 16);
}

// ---- dtype sniffer: flag=1 if input stream is bf16, 0 if fp32.
// Wave-parallel: 64 lanes x 32 samples (same 2048-element sample set as the
// original serial version -> identical decision), shfl reduce.
__global__ void k_sniff(const u16* __restrict__ x, int* __restrict__ flag) {
  const int lane = threadIdx.x & 63;
  int cnt = 0;
#pragma unroll
  for (int k = 0; k < 32; ++k) {
    u16 u = x[2 * (lane + 64 * k)];
    int e = (u >> 7) & 0xFF;
    cnt += (e >= 100 && e <= 140) ? 1 : 0;
  }
#pragma unroll
  for (int d = 32; d > 0; d >>= 1) cnt += __shfl_down(cnt, d, 64);
  if (lane == 0) *flag = (cnt >= 1024) ? 1 : 0;
}

// ---- canonicalize input to bf16 (copy if bf16, round if fp32)
__global__ __launch_bounds__(256) void k_convert(const void* __restrict__ src,
                                                 u16* __restrict__ dst,
                                                 const int* __restrict__ flag, long n) {
  long i = ((long)blockIdx.x * 256 + threadIdx.x) * 4;
  if (i >= n) return;
  if (*flag) {
    *(us4*)(dst + i) = *(const us4*)((const u16*)src + i);
  } else {
    const float* s = (const float*)src;
    us4 o;
#pragma unroll
    for (int e = 0; e < 4; ++e) o[e] = f2b(s[i + e]);
    *(us4*)(dst + i) = o;
  }
}

// async global->LDS, 16B per lane; LDS dest = wave-uniform base + lane*16
__device__ __forceinline__ void ldsg16(const u16* g, u16* l) {
  auto gp = reinterpret_cast<__attribute__((address_space(1))) void*>(
      reinterpret_cast<uintptr_t>(const_cast<u16*>(g)));
  auto lp = reinterpret_cast<__attribute__((address_space(3))) void*>(
      (unsigned int)reinterpret_cast<uintptr_t>(l));
  __builtin_amdgcn_global_load_lds(gp, lp, 16, 0, 0);
}

// compiler-fence + raw HW barrier (NO vmcnt drain -- that is the point)
__device__ __forceinline__ void bar() {
  asm volatile("" ::: "memory");
  __builtin_amdgcn_s_barrier();
  asm volatile("" ::: "memory");
}
// stage 256 rows x 64 k (one operand K-tile = 32KB): 4 wide loads/thread
__device__ __forceinline__ void stage4(const u16* g, u16* l, long s64) {
  ldsg16(g, l);
  ldsg16(g + s64, l + 4096);
  ldsg16(g + 2 * s64, l + 8192);
  ldsg16(g + 3 * s64, l + 12288);
}

#define LDA4(OFF) \
  _Pragma("unroll") \
  for (int mi = 0; mi < 4; ++mi) af[mi] = *(const bf16x8*)(pA + mi * 2048 + (OFF))

#define MFMA16(AC0, BF) \
  _Pragma("unroll") \
  for (int mi = 0; mi < 4; ++mi) \
    _Pragma("unroll") \
    for (int ni = 0; ni < 4; ++ni) \
      acc[(AC0) + mi][ni] = __builtin_amdgcn_mfma_f32_16x16x32_bf16(af[mi], BF[ni], acc[(AC0) + mi][ni], 0, 0, 0)

// ---- 256x256 tile GEMM engine, TWO-SEGMENT K (segment2 may be empty, K2=0),
// 512 threads, 8 waves (2M x 4N), BK=64, double-buffered 128KB LDS.
// Deep pipeline with COUNTED vmcnt: tile kt+2's stage is issued into buf[kt&1]
// right after ph3's ds_reads complete (lgkmcnt(0)+barrier frees the buffer),
// BEFORE waiting for tile kt+1 -> the wait is vmcnt(8), never a drain-to-0.
// Each tile's loads get a full kt (~4 phases) of latency cover.
// LDS swizzle: physical 16B-chunk = logical ^ ((row>>1)&7); linear LDS dest,
// inverse permutation applied on the global source column (both-sides rule).
// acc[8][4]: rows wm*128 + mi*16 + quad*4 + e, cols wn*64 + ni*16 + c16.
// Requires total NT = (K1+K2)/64 >= 2, K1 >= 128.
__device__ __forceinline__ void gemm256s(
    const u16* __restrict__ A1, long lda1,
    const u16* __restrict__ B1, long ldb1, int K1,
    const u16* __restrict__ A2, long lda2,
    const u16* __restrict__ B2, long ldb2, int K2,
    u16* sA, u16* sB, floatx4 acc[8][4])
{
  const int t = threadIdx.x, w = t >> 6, lane = t & 63;
  const int quad = lane >> 4, m16 = lane & 15;
  const int wm = w >> 2, wn = w & 3;
  // staging: thread t -> row (t>>3)+64*i, source chunk = (t&7) ^ ((t>>4)&7)
  const int csw = ((t & 7) ^ ((t >> 4) & 7)) << 3;
  const long row = t >> 3;
  const u16* ga1 = A1 + row * lda1 + csw;
  const u16* gb1 = B1 + row * ldb1 + csw;
  const u16* ga2 = A2 + row * lda2 + csw;
  const u16* gb2 = B2 + row * ldb2 + csw;
  const long a641 = 64l * lda1, b641 = 64l * ldb1;
  const long a642 = 64l * lda2, b642 = 64l * ldb2;
  u16* lA = sA + w * 512;                              // wave-uniform LDS base
  u16* lB = sB + w * 512;
  const char* cA = (const char*)sA;
  const char* cB = (const char*)sB;
  const int lx = ((m16 >> 1) & 7) << 4;                // reader swizzle (bytes)
  const int raB = (wm * 128 + m16) << 7;               // A frag row base (bytes)
  const int rbB = (wn * 64 + m16) << 7;                // B frag row base
  const int kq0 = (quad << 4) ^ lx;                    // k 0..31 slot
  const int kq1 = (64 + (quad << 4)) ^ lx;             // k 32..63 slot
  const int NT1 = K1 >> 6, NT = (K1 + K2) >> 6;

  auto STAGE = [&](int tt, int buf) {                  // tile tt -> buffer buf
    const u16 *sa, *sb; long s64a, s64b;
    if (tt < NT1) { sa = ga1 + (long)tt * 64;         sb = gb1 + (long)tt * 64;         s64a = a641; s64b = b641; }
    else          { long u = tt - NT1; sa = ga2 + u * 64; sb = gb2 + u * 64;            s64a = a642; s64b = b642; }
    stage4(sa, lA + (buf << 14), s64a);
    stage4(sb, lB + (buf << 14), s64b);
  };

  STAGE(0, 0);
  STAGE(1, 1);
  asm volatile("s_waitcnt vmcnt(8)" ::: "memory");     // tile 0 resident, tile 1 in flight
  bar();

  for (int kt = 0; kt < NT; ++kt) {
    const char* pA = cA + ((kt & 1) << 15) + raB;
    const char* pB = cB + ((kt & 1) << 15) + rbB;
    bf16x8 af[4], bf0[4], bf1[4];

    // phase 0: rows wm*128+0..63, k 0-31
    LDA4(kq0);
#pragma unroll
    for (int ni = 0; ni < 4; ++ni) bf0[ni] = *(const bf16x8*)(pB + ni * 2048 + kq0);
    bar();
    __builtin_amdgcn_s_setprio(1);
    MFMA16(0, bf0);
    __builtin_amdgcn_s_setprio(0);
    bar();

    // phase 1: rows wm*128+0..63, k 32-63
    LDA4(kq1);
#pragma unroll
    for (int ni = 0; ni < 4; ++ni) bf1[ni] = *(const bf16x8*)(pB + ni * 2048 + kq1);
    bar();
    __builtin_amdgcn_s_setprio(1);
    MFMA16(0, bf1);
    __builtin_amdgcn_s_setprio(0);
    bar();

    // phase 2: rows wm*128+64..127, k 0-31 (bf0 reused from registers)
    LDA4(8192 + kq0);
    bar();
    __builtin_amdgcn_s_setprio(1);
    MFMA16(4, bf0);
    __builtin_amdgcn_s_setprio(0);
    bar();

    // phase 3: rows wm*128+64..127, k 32-63. After these ds_reads complete
    // (lgkm0 + barrier), buf[kt&1] is free: issue tile kt+2 into it, THEN do
    // the counted wait for tile kt+1 (8 younger loads stay outstanding).
    LDA4(8192 + kq1);
    asm volatile("s_waitcnt lgkmcnt(0)" ::: "memory");
    __builtin_amdgcn_sched_barrier(0);
    bar();
    __builtin_amdgcn_sched_barrier(0);
    if (kt + 2 < NT) STAGE(kt + 2, kt & 1);
    __builtin_amdgcn_s_setprio(1);
    MFMA16(4, bf1);
    __builtin_amdgcn_s_setprio(0);
    __builtin_amdgcn_sched_barrier(0);
    if (kt + 2 < NT)      { asm volatile("s_waitcnt vmcnt(8)" ::: "memory"); }
    else if (kt + 1 < NT) { asm volatile("s_waitcnt vmcnt(0)" ::: "memory"); }
    bar();
  }
}

// ---- legacy 128x128 engine, kept for k_scores (mask-dominated, small)
__device__ __forceinline__ void gemm128(
    const u16* __restrict__ A, long lda,
    const u16* __restrict__ B, long ldb,
    int K, u16* sA, u16* sB, floatx4 acc[4][4])
{
  const int t = threadIdx.x, w = t >> 6, lane = t & 63;
  const int m16 = lane & 15, quad = lane >> 4;
  const int wm = w >> 1, wn = w & 1;
  const int sq = (lane & 3) ^ ((lane >> 3) & 3);          // permuted colgroup
  const u16* ga = A + (long)(t >> 2) * lda + sq * 8;
  const u16* gb = B + (long)(t >> 2) * ldb + sq * 8;
  const long a64 = 64l * lda, b64 = 64l * ldb;
  u16* lA = sA + w * 512;
  u16* lB = sB + w * 512;
  const char* cA = (const char*)sA;
  const char* cB = (const char*)sB;
  const int slot = quad ^ ((m16 >> 1) & 3);
  const int aoff = wm * 4096 + m16 * 64 + slot * 16;
  const int boff = wn * 4096 + m16 * 64 + slot * 16;
  for (int k0 = 0; k0 < K; k0 += 32) {
    __syncthreads();
    ldsg16(ga, lA);
    ldsg16(ga + a64, lA + 2048);
    ldsg16(gb, lB);
    ldsg16(gb + b64, lB + 2048);
    ga += 32; gb += 32;
    __syncthreads();
    bf16x8 af[4], bfr[4];
#pragma unroll
    for (int i = 0; i < 4; ++i) af[i]  = *(const bf16x8*)(cA + aoff + i * 1024);
#pragma unroll
    for (int i = 0; i < 4; ++i) bfr[i] = *(const bf16x8*)(cB + boff + i * 1024);
#pragma unroll
    for (int im = 0; im < 4; ++im)
#pragma unroll
      for (int in = 0; in < 4; ++in)
        acc[im][in] = __builtin_amdgcn_mfma_f32_16x16x32_bf16(af[im], bfr[in], acc[im][in], 0, 0, 0);
  }
}

// ---- projections: Y = elu?(X @ W^T); mode 1 elu+1, 2 transposed store (V -> Vt)
// blockIdx XCD-swizzled: 32 consecutive logical ids per XCD -> X/W panel L2 reuse.
__global__ __launch_bounds__(512, 2) void k_proj2(
    const u16* __restrict__ X, const u16* __restrict__ Wt, u16* __restrict__ Y, int mode)
{
  __shared__ __align__(16) u16 sm[65536];
  floatx4 acc[8][4] = {};
  const int raw = blockIdx.x;             // 256 blocks, 256 % 8 == 0 -> bijective
  const int id = ((raw & 7) << 5) | (raw >> 3);
  const int m0 = (id >> 2) * 256, n0 = (id & 3) * 256;
  gemm256s(X + (long)m0 * DM, DM, Wt + (long)n0 * DM, DM, DM,
           X, DM, Wt, DM, 0, sm, sm + 32768, acc);
  const int t = threadIdx.x, w = t >> 6, lane = t & 63;
  const int wm = w >> 2, wn = w & 3, quad = lane >> 4, c16 = lane & 15;
#pragma unroll
  for (int mi = 0; mi < 8; ++mi)
#pragma unroll
    for (int ni = 0; ni < 4; ++ni) {
      const int gr = m0 + wm * 128 + mi * 16 + quad * 4;
      const int gc = n0 + wn * 64 + ni * 16 + c16;
      floatx4 v = acc[mi][ni];
      if (mode == 2) {
        us4 o;
#pragma unroll
        for (int e = 0; e < 4; ++e) o[e] = f2b(v[e]);
        *(us4*)(Y + (long)gc * ROWS + gr) = o;      // Vt[model][row]
      } else {
#pragma unroll
        for (int e = 0; e < 4; ++e) {
          float u = v[e];
          u = u > 0.f ? u + 1.f : __expf(u);        // elu(u)+1
          Y[(long)(gr + e) * DM + gc] = f2b(u);
        }
      }
    }
}

// ---- K[ROWS][DM] -> Kt[DM][ROWS]
__global__ __launch_bounds__(256) void k_transpose(const u16* __restrict__ src, u16* __restrict__ dst)
{
  const int t = threadIdx.x;
  const int sx = t & 15, sy = t >> 4;
  const long r0 = (long)blockIdx.x * 128 + sy * 8;
  const long c0 = (long)blockIdx.y * 128 + sx * 8;
  us8 r[8];
#pragma unroll
  for (int v = 0; v < 8; ++v) r[v] = *(const us8*)(src + (r0 + v) * DM + c0);
#pragma unroll
  for (int u = 0; u < 8; ++u) {
    us8 o;
#pragma unroll
    for (int v = 0; v < 8; ++v) o[v] = r[v][u];
    *(us8*)(dst + (c0 + u) * ROWS + r0) = o;
  }
}

// ---- per-chunk K column sums
__global__ __launch_bounds__(256) void k_cksum(const u16* __restrict__ Kp, float* __restrict__ cs)
{
  const int id = blockIdx.x * 256 + threadIdx.x;
  const int i = id & 1023, b = (id >> 10) & 3, j = id >> 12;
  const u16* p = Kp + ((long)j * CR + b) * DM + i;
  float a = 0.f;
#pragma unroll 8
  for (int tl = 0; tl < CHUNK; ++tl) a += b2f(p[(long)tl * BB * DM]);
  cs[id] = a;
}

// ---- z cumsum (fp32 running, bf16 store)
__global__ __launch_bounds__(256) void k_zfill(const u16* __restrict__ Kp,
                                               const float* __restrict__ cs,
                                               u16* __restrict__ z)
{
  const int id = blockIdx.x * 256 + threadIdx.x;
  const int i = id & 1023, b = (id >> 10) & 3, j = id >> 12;
  float a = 0.f;
  for (int j2 = 0; j2 < j; ++j2) a += cs[j2 * 4096 + b * 1024 + i];
  const u16* p = Kp + ((long)j * CR + b) * DM + i;
  u16* q = z + ((long)j * CR + b) * DM + i;
  for (int tl = 0; tl < CHUNK; ++tl) {
    a += b2f(p[(long)tl * BB * DM]);
    q[(long)tl * BB * DM] = f2b(a);
  }
}

// ---- per-chunk G[j][m][i] = sum_{r in chunk} V[r][m] K[r][i].  XCD j-grouped.
__global__ __launch_bounds__(512, 2) void k_gemm_g2(
    const u16* __restrict__ Vt, const u16* __restrict__ Kt, u16* __restrict__ G)
{
  __shared__ __align__(16) u16 sm[65536];
  floatx4 acc[8][4] = {};
  const int id = blockIdx.x;           // 512
  const int x = id & 7, s = id >> 3;   // x = XCD, s = slot on that XCD
  const int j = x + 8 * (s >> 4);      // all 16 blocks of chunk j on XCD x
  const int nm = s & 15;
  const int n0 = (nm & 3) * 256;       // key index i
  const int m0 = (nm >> 2) * 256;      // model index m
  gemm256s(Vt + (long)m0 * ROWS + j * CR, ROWS,
           Kt + (long)n0 * ROWS + j * CR, ROWS, CR,
           Vt, ROWS, Kt, ROWS, 0, sm, sm + 32768, acc);
  const int t = threadIdx.x, w = t >> 6, lane = t & 63;
  const int wm = w >> 2, wn = w & 3, quad = lane >> 4, c16 = lane & 15;
  u16* Gj = G + (long)j * DM * DM;
#pragma unroll
  for (int mi = 0; mi < 8; ++mi)
#pragma unroll
    for (int ni = 0; ni < 4; ++ni) {
      const int gr = m0 + wm * 128 + mi * 16 + quad * 4;
      const int gc = n0 + wn * 64 + ni * 16 + c16;
      floatx4 v = acc[mi][ni];
#pragma unroll
      for (int e = 0; e < 4; ++e) Gj[(long)(gr + e) * DM + gc] = f2b(v[e]);
    }
}

// ---- exclusive prefix over chunks
__global__ __launch_bounds__(256) void k_prefix(u16* __restrict__ G)
{
  const long id = (long)blockIdx.x * 256 + threadIdx.x;
  float a = 0.f;
#pragma unroll
  for (int j = 0; j < NC; ++j) {
    u16* p = G + (long)j * DM * DM + id;
    float g = b2f(*p);
    *p = f2b(a);
    a += g;
  }
}

// ---- intra-chunk scores, masked; upper-triangle blocks skip the GEMM. XCD j-grouped.
__global__ __launch_bounds__(256) void k_scores(
    const u16* __restrict__ Q, const u16* __restrict__ Kp, u16* __restrict__ P)
{
  __shared__ __align__(16) u16 sA[4096];
  __shared__ __align__(16) u16 sB[4096];
  floatx4 acc[4][4] = {};
  const int id = blockIdx.x;           // 512
  const int x = id & 7, s = id >> 3;   // s: 0..63
  const int j = x + 8 * (s >> 4);
  const int nm = s & 15;
  const int n0 = (nm & 3) * 128;
  const int m0 = (nm >> 2) * 128;
  if (n0 <= m0) {   // lower/diagonal blocks only; others fully masked -> zeros
    gemm128(Q + ((long)j * CR + m0) * DM, DM,
            Kp + ((long)j * CR + n0) * DM, DM, DM, sA, sB, acc);
  }
  const int t = threadIdx.x, lane = t & 63, w = t >> 6;
  const int wm = w >> 1, wn = w & 1, quad = lane >> 4, c16 = lane & 15;
  u16* Pj = P + (long)j * CR * CR;
#pragma unroll
  for (int im = 0; im < 4; ++im)
#pragma unroll
    for (int in = 0; in < 4; ++in) {
      const int gc = n0 + wn * 64 + in * 16 + c16;
      const int gr = m0 + wm * 64 + im * 16 + quad * 4;
      const bool valid = (gc <= gr + 3);
      floatx4 v = acc[im][in];
#pragma unroll
      for (int e = 0; e < 4; ++e)
        Pj[(long)(gr + e) * CR + gc] = valid ? f2b(v[e]) : (u16)0;
    }
}

// ---- denom[row] = q_row . z_row
__global__ __launch_bounds__(256) void k_denom(
    const u16* __restrict__ Q, const u16* __restrict__ z, float* __restrict__ denom)
{
  const int w = threadIdx.x >> 6, lane = threadIdx.x & 63;
  const long row = (long)blockIdx.x * 4 + w;
  const u16* q = Q + row * DM;
  const u16* zz = z + row * DM;
  float s = 0.f;
#pragma unroll
  for (int p = 0; p < 2; ++p) {
    const int off = lane * 8 + p * 512;
    us8 q8 = *(const us8*)(q + off);
    us8 z8 = *(const us8*)(zz + off);
#pragma unroll
    for (int e = 0; e < 8; ++e) s += b2f(q8[e]) * b2f(z8[e]);
  }
#pragma unroll
  for (int d = 32; d > 0; d >>= 1) s += __shfl_down(s, d, 64);
  if (lane == 0) denom[row] = s;
}

// ---- y = (P @ V + Q @ S_chunkstart) / denom. 256x256 tiles, fused emit,
//      XCD j-grouped. SINGLE two-segment pipelined GEMM: segment1 = PV with K
//      truncated to m0+256 (P cols beyond are masked zeros), segment2 = Q@St.
__global__ __launch_bounds__(512, 2) void k_out2(
    const u16* __restrict__ P, const u16* __restrict__ Vt,
    const u16* __restrict__ Q, const u16* __restrict__ St,
    const float* __restrict__ denom, void* __restrict__ out,
    const int* __restrict__ flag)
{
  __shared__ __align__(16) u16 sm[65536];
  floatx4 acc[8][4] = {};
  const int id = blockIdx.x;           // 256
  const int x = id & 7, s = id >> 3;   // s: 0..31
  const int j = x + 8 * (s >> 3);      // 8 blocks of chunk j contiguous on XCD x
  const int nm = s & 7;
  const int n0 = (nm & 3) * 256;       // model col
  const int m0 = (nm >> 2) * 256;      // row in chunk
  gemm256s(P + (long)j * CR * CR + (long)m0 * CR, CR,
           Vt + (long)n0 * ROWS + j * CR, ROWS, m0 + 256,
           Q + ((long)j * CR + m0) * DM, DM,
           St + (long)j * DM * DM + (long)n0 * DM, DM, DM,
           sm, sm + 32768, acc);
  const int t = threadIdx.x, w = t >> 6, lane = t & 63;
  const int wm = w >> 2, wn = w & 3, quad = lane >> 4, c16 = lane & 15;
  const int isf16 = *flag;
  float* of = (float*)out;
  u16* ob = (u16*)out;
#pragma unroll
  for (int mi = 0; mi < 8; ++mi)
#pragma unroll
    for (int ni = 0; ni < 4; ++ni) {
      const int gc = n0 + wn * 64 + ni * 16 + c16;
      const int grl = m0 + wm * 128 + mi * 16 + quad * 4;
      const long gr = (long)j * CR + grl;
      floatx4 v = acc[mi][ni];
#pragma unroll
      for (int e = 0; e < 4; ++e) {
        const float d = denom[gr + e];
        const float y = v[e] / d;
        if (isf16) ob[(gr + e) * DM + gc] = f2b(y);
        else       of[(gr + e) * DM + gc] = y;
      }
    }
}

extern "C" void kernel_launch(void* const* d_in, const int* in_sizes, int n_in,
                              void* d_out, int out_size, void* d_ws, size_t ws_size,
                              hipStream_t stream)
{
  char* ws = (char*)d_ws;
  u16*  xc  = (u16*)(ws);              // region A [32M]: xc, later z
  u16*  z   = (u16*)(ws);
  u16*  Q   = (u16*)(ws + 32 * MB);    // region B [32M]
  u16*  K   = (u16*)(ws + 64 * MB);    // region C [32M]
  u16*  Kt  = (u16*)(ws + 96 * MB);    // region D [32M]: Kt, later P (16M)
  u16*  P   = (u16*)(ws + 96 * MB);
  u16*  Vt  = (u16*)(ws + 128 * MB);   // region E [32M]
  u16*  G   = (u16*)(ws + 160 * MB);   // region F [64M] (St after k_prefix)
  u16*  Wqc = (u16*)(ws + 224 * MB);
  u16*  Wkc = (u16*)(ws + 226 * MB);
  u16*  Wvc = (u16*)(ws + 228 * MB);
  float* cs = (float*)(ws + 230 * MB);
  float* dn = (float*)(ws + 230 * MB + 524288);
  int* flag = (int*)(ws + 230 * MB + 524288 + 65536);

  dim3 blk(256), blk5(512);
  k_sniff<<<1, 64, 0, stream>>>((const u16*)d_in[0], flag);
  k_convert<<<16384, blk, 0, stream>>>(d_in[0], xc, flag, (long)ROWS * DM);
  k_convert<<<1024, blk, 0, stream>>>(d_in[1], Wqc, flag, (long)DM * DM);
  k_convert<<<1024, blk, 0, stream>>>(d_in[2], Wkc, flag, (long)DM * DM);
  k_convert<<<1024, blk, 0, stream>>>(d_in[3], Wvc, flag, (long)DM * DM);
  k_proj2<<<dim3(256), blk5, 0, stream>>>(xc, Wqc, Q, 1);
  k_proj2<<<dim3(256), blk5, 0, stream>>>(xc, Wkc, K, 1);
  k_proj2<<<dim3(256), blk5, 0, stream>>>(xc, Wvc, Vt, 2);
  k_transpose<<<dim3(128, 8), blk, 0, stream>>>(K, Kt);
  k_cksum<<<dim3(512), blk, 0, stream>>>(K, cs);
  k_zfill<<<dim3(512), blk, 0, stream>>>(K, cs, z);       // z overlays dead xc
  k_gemm_g2<<<dim3(512), blk5, 0, stream>>>(Vt, Kt, G);
  k_prefix<<<dim3(4096), blk, 0, stream>>>(G);
  k_scores<<<dim3(512), blk, 0, stream>>>(Q, K, P);       // P overlays dead Kt
  k_denom<<<dim3(4096), blk, 0, stream>>>(Q, z, dn);
  k_out2<<<dim3(256), blk5, 0, stream>>>(P, Vt, Q, G, dn, d_out, flag);
}

// Round 5
// 438.277 us; speedup vs baseline: 1.0227x; 1.0227x over previous
//
#include <hip/hip_runtime.h>
#include <hip/hip_bf16.h>
#include <stdint.h>

typedef unsigned short u16;
typedef __attribute__((ext_vector_type(8))) __bf16 bf16x8;
typedef __attribute__((ext_vector_type(4))) float floatx4;
typedef __attribute__((ext_vector_type(8))) unsigned short us8;
typedef __attribute__((ext_vector_type(4))) unsigned short us4;

#define TT 4096
#define BB 4
#define DM 1024
#define ROWS (TT * BB)      // 16384 flattened (t,b) rows
#define CHUNK 128           // timesteps per chunk
#define CR (CHUNK * BB)     // 512 rows per chunk
#define NC (TT / CHUNK)     // 32 chunks
#define MB (1024l * 1024l)

__device__ __forceinline__ float b2f(u16 x) {
  union { unsigned int u; float f; } v; v.u = ((unsigned int)x) << 16; return v.f;
}
__device__ __forceinline__ u16 f2b(float f) {
  union { float f; unsigned int u; } v; v.f = f;
  unsigned int r = v.u + 0x7fffu + ((v.u >> 16) & 1u);   // RNE
  return (u16)(r >> 16);
}

// ---- dtype sniffer: flag=1 if input stream is bf16, 0 if fp32.
// Wave-parallel: 64 lanes x 32 samples (same 2048-element sample set as the
// original serial version -> identical decision), shfl reduce.
__global__ void k_sniff(const u16* __restrict__ x, int* __restrict__ flag) {
  const int lane = threadIdx.x & 63;
  int cnt = 0;
#pragma unroll
  for (int k = 0; k < 32; ++k) {
    u16 u = x[2 * (lane + 64 * k)];
    int e = (u >> 7) & 0xFF;
    cnt += (e >= 100 && e <= 140) ? 1 : 0;
  }
#pragma unroll
  for (int d = 32; d > 0; d >>= 1) cnt += __shfl_down(cnt, d, 64);
  if (lane == 0) *flag = (cnt >= 1024) ? 1 : 0;
}

// ---- canonicalize input to bf16 (copy if bf16, round if fp32)
__global__ __launch_bounds__(256) void k_convert(const void* __restrict__ src,
                                                 u16* __restrict__ dst,
                                                 const int* __restrict__ flag, long n) {
  long i = ((long)blockIdx.x * 256 + threadIdx.x) * 4;
  if (i >= n) return;
  if (*flag) {
    *(us4*)(dst + i) = *(const us4*)((const u16*)src + i);
  } else {
    const float* s = (const float*)src;
    us4 o;
#pragma unroll
    for (int e = 0; e < 4; ++e) o[e] = f2b(s[i + e]);
    *(us4*)(dst + i) = o;
  }
}

// async global->LDS, 16B per lane; LDS dest = wave-uniform base + lane*16
__device__ __forceinline__ void ldsg16(const u16* g, u16* l) {
  auto gp = reinterpret_cast<__attribute__((address_space(1))) void*>(
      reinterpret_cast<uintptr_t>(const_cast<u16*>(g)));
  auto lp = reinterpret_cast<__attribute__((address_space(3))) void*>(
      (unsigned int)reinterpret_cast<uintptr_t>(l));
  __builtin_amdgcn_global_load_lds(gp, lp, 16, 0, 0);
}

// compiler-fence + raw HW barrier (no implicit vmcnt drain)
__device__ __forceinline__ void bar() {
  asm volatile("" ::: "memory");
  __builtin_amdgcn_s_barrier();
  asm volatile("" ::: "memory");
}
// stage 256 rows x 64 k (one operand K-tile = 32KB): 4 wide loads/thread
__device__ __forceinline__ void stage4(const u16* g, u16* l, long s64) {
  ldsg16(g, l);
  ldsg16(g + s64, l + 4096);
  ldsg16(g + 2 * s64, l + 8192);
  ldsg16(g + 3 * s64, l + 12288);
}

#define LD4(DST, BASE, OFF) \
  _Pragma("unroll") \
  for (int ii = 0; ii < 4; ++ii) DST[ii] = *(const bf16x8*)((BASE) + ii * 2048 + (OFF))

#define MFMA16(AC0, AF, BF) \
  _Pragma("unroll") \
  for (int mi = 0; mi < 4; ++mi) \
    _Pragma("unroll") \
    for (int ni = 0; ni < 4; ++ni) \
      acc[(AC0) + mi][ni] = __builtin_amdgcn_mfma_f32_16x16x32_bf16(AF[mi], BF[ni], acc[(AC0) + mi][ni], 0, 0, 0)

// ---- 256x256 tile GEMM engine, TWO-SEGMENT K (segment2 may be empty, K2=0),
// 512 threads, 8 waves (2M x 4N), BK=64, double-buffered 128KB LDS.
// BARRIER-LIGHT schedule: the whole K-tile is resident in buf[kt&1] and
// staging targets the other buffer, so NO intra-tile barriers are needed.
// Per K-tile only two sync points:
//   (1) lgkmcnt(0)+barrier  -> all waves done READING cur, safe to overwrite
//   (2) counted vmcnt(8)+barrier -> tile kt+1 resident for everyone
// VMCNT ARITHMETIC (bug fixed this round): one STAGE = 2x stage4 = 8
// global_load_lds per thread. Prologue: 16 outstanding -> vmcnt(8) drains
// exactly tile 0's 8 (in-order retirement), tile 1's 8 stay in flight.
// Main loop: outstanding = kt+1's 8 + kt+2's 8 -> vmcnt(8) drains kt+1,
// keeps kt+2 in flight. Never a drain-to-0 in the main loop.
// Between the sync points the 24 ds_reads and 64 MFMAs interleave freely
// (compiler emits fine-grained lgkmcnt; waves drift so one wave's MFMA
// covers another's reads). The 4th MFMA quadrant (register-only) runs
// between STAGE-issue and the counted vmcnt, covering the load issue.
// LDS swizzle: physical 16B-chunk = logical ^ ((row>>1)&7); linear LDS dest,
// inverse permutation applied on the global source column (both-sides rule).
// acc[8][4]: rows wm*128 + mi*16 + quad*4 + e, cols wn*64 + ni*16 + c16.
// Requires total NT = (K1+K2)/64 >= 2, K1 multiple of 64.
__device__ __forceinline__ void gemm256s(
    const u16* __restrict__ A1, long lda1,
    const u16* __restrict__ B1, long ldb1, int K1,
    const u16* __restrict__ A2, long lda2,
    const u16* __restrict__ B2, long ldb2, int K2,
    u16* sA, u16* sB, floatx4 acc[8][4])
{
  const int t = threadIdx.x, w = t >> 6, lane = t & 63;
  const int quad = lane >> 4, m16 = lane & 15;
  const int wm = w >> 2, wn = w & 3;
  // staging: thread t -> row (t>>3)+64*i, source chunk = (t&7) ^ ((t>>4)&7)
  const int csw = ((t & 7) ^ ((t >> 4) & 7)) << 3;
  const long row = t >> 3;
  const u16* ga1 = A1 + row * lda1 + csw;
  const u16* gb1 = B1 + row * ldb1 + csw;
  const u16* ga2 = A2 + row * lda2 + csw;
  const u16* gb2 = B2 + row * ldb2 + csw;
  const long a641 = 64l * lda1, b641 = 64l * ldb1;
  const long a642 = 64l * lda2, b642 = 64l * ldb2;
  u16* lA = sA + w * 512;                              // wave-uniform LDS base
  u16* lB = sB + w * 512;
  const char* cA = (const char*)sA;
  const char* cB = (const char*)sB;
  const int lx = ((m16 >> 1) & 7) << 4;                // reader swizzle (bytes)
  const int raB = (wm * 128 + m16) << 7;               // A frag row base (bytes)
  const int rbB = (wn * 64 + m16) << 7;                // B frag row base
  const int kq0 = (quad << 4) ^ lx;                    // k 0..31 slot
  const int kq1 = (64 + (quad << 4)) ^ lx;             // k 32..63 slot
  const int NT1 = K1 >> 6, NT = (K1 + K2) >> 6;

  auto STAGE = [&](int tt, int buf) {                  // tile tt -> buffer buf
    const u16 *sa, *sb; long s64a, s64b;
    if (tt < NT1) { sa = ga1 + (long)tt * 64;          sb = gb1 + (long)tt * 64;          s64a = a641; s64b = b641; }
    else          { long u = tt - NT1; sa = ga2 + u * 64; sb = gb2 + u * 64;              s64a = a642; s64b = b642; }
    stage4(sa, lA + (buf << 14), s64a);
    stage4(sb, lB + (buf << 14), s64b);
  };

  STAGE(0, 0);
  STAGE(1, 1);
  asm volatile("s_waitcnt vmcnt(8)" ::: "memory");     // tile 0 resident, tile 1 in flight
  bar();

  for (int kt = 0; kt < NT; ++kt) {
    const char* pA = cA + ((kt & 1) << 15) + raB;
    const char* pB = cB + ((kt & 1) << 15) + rbB;
    bf16x8 aX[4], aY[4], b0[4], b1[4];

    // quadrant reads + MFMAs, no barriers: compiler interleaves via lgkmcnt
    LD4(aX, pA, kq0);                 // A lo rows, k 0-31
    LD4(b0, pB, kq0);                 // B k 0-31
    LD4(aY, pA, kq1);                 // A lo rows, k 32-63
    LD4(b1, pB, kq1);                 // B k 32-63
    MFMA16(0, aX, b0);                // q0
    LD4(aX, pA, 8192 + kq0);          // A hi rows, k 0-31 (reuse regs)
    MFMA16(0, aY, b1);                // q1
    LD4(aY, pA, 8192 + kq1);          // A hi rows, k 32-63
    MFMA16(4, aX, b0);                // q2

    // (1) all my reads from cur complete -> signal buffer free
    asm volatile("s_waitcnt lgkmcnt(0)" ::: "memory");
    __builtin_amdgcn_sched_barrier(0);
    bar();
    // overwrite freed buffer with tile kt+2 while q3 computes from registers
    if (kt + 2 < NT) STAGE(kt + 2, kt & 1);
    __builtin_amdgcn_s_setprio(1);
    MFMA16(4, aY, b1);                // q3 covers the load issue
    __builtin_amdgcn_s_setprio(0);
    __builtin_amdgcn_sched_barrier(0);
    // (2) tile kt+1 resident (kt+2's 8 loads stay in flight)
    if (kt + 2 < NT)      { asm volatile("s_waitcnt vmcnt(8)" ::: "memory"); }
    else if (kt + 1 < NT) { asm volatile("s_waitcnt vmcnt(0)" ::: "memory"); }
    bar();
  }
}

// ---- legacy 128x128 engine, kept for k_scores (mask-dominated, small)
__device__ __forceinline__ void gemm128(
    const u16* __restrict__ A, long lda,
    const u16* __restrict__ B, long ldb,
    int K, u16* sA, u16* sB, floatx4 acc[4][4])
{
  const int t = threadIdx.x, w = t >> 6, lane = t & 63;
  const int m16 = lane & 15, quad = lane >> 4;
  const int wm = w >> 1, wn = w & 1;
  const int sq = (lane & 3) ^ ((lane >> 3) & 3);          // permuted colgroup
  const u16* ga = A + (long)(t >> 2) * lda + sq * 8;
  const u16* gb = B + (long)(t >> 2) * ldb + sq * 8;
  const long a64 = 64l * lda, b64 = 64l * ldb;
  u16* lA = sA + w * 512;
  u16* lB = sB + w * 512;
  const char* cA = (const char*)sA;
  const char* cB = (const char*)sB;
  const int slot = quad ^ ((m16 >> 1) & 3);
  const int aoff = wm * 4096 + m16 * 64 + slot * 16;
  const int boff = wn * 4096 + m16 * 64 + slot * 16;
  for (int k0 = 0; k0 < K; k0 += 32) {
    __syncthreads();
    ldsg16(ga, lA);
    ldsg16(ga + a64, lA + 2048);
    ldsg16(gb, lB);
    ldsg16(gb + b64, lB + 2048);
    ga += 32; gb += 32;
    __syncthreads();
    bf16x8 af[4], bfr[4];
#pragma unroll
    for (int i = 0; i < 4; ++i) af[i]  = *(const bf16x8*)(cA + aoff + i * 1024);
#pragma unroll
    for (int i = 0; i < 4; ++i) bfr[i] = *(const bf16x8*)(cB + boff + i * 1024);
#pragma unroll
    for (int im = 0; im < 4; ++im)
#pragma unroll
      for (int in = 0; in < 4; ++in)
        acc[im][in] = __builtin_amdgcn_mfma_f32_16x16x32_bf16(af[im], bfr[in], acc[im][in], 0, 0, 0);
  }
}

// ---- projections: Y = elu?(X @ W^T); mode 1 elu+1, 2 transposed store (V -> Vt)
// blockIdx XCD-swizzled: 32 consecutive logical ids per XCD -> X/W panel L2 reuse.
__global__ __launch_bounds__(512, 2) void k_proj2(
    const u16* __restrict__ X, const u16* __restrict__ Wt, u16* __restrict__ Y, int mode)
{
  __shared__ __align__(16) u16 sm[65536];
  floatx4 acc[8][4] = {};
  const int raw = blockIdx.x;             // 256 blocks, 256 % 8 == 0 -> bijective
  const int id = ((raw & 7) << 5) | (raw >> 3);
  const int m0 = (id >> 2) * 256, n0 = (id & 3) * 256;
  gemm256s(X + (long)m0 * DM, DM, Wt + (long)n0 * DM, DM, DM,
           X, DM, Wt, DM, 0, sm, sm + 32768, acc);
  const int t = threadIdx.x, w = t >> 6, lane = t & 63;
  const int wm = w >> 2, wn = w & 3, quad = lane >> 4, c16 = lane & 15;
#pragma unroll
  for (int mi = 0; mi < 8; ++mi)
#pragma unroll
    for (int ni = 0; ni < 4; ++ni) {
      const int gr = m0 + wm * 128 + mi * 16 + quad * 4;
      const int gc = n0 + wn * 64 + ni * 16 + c16;
      floatx4 v = acc[mi][ni];
      if (mode == 2) {
        us4 o;
#pragma unroll
        for (int e = 0; e < 4; ++e) o[e] = f2b(v[e]);
        *(us4*)(Y + (long)gc * ROWS + gr) = o;      // Vt[model][row]
      } else {
#pragma unroll
        for (int e = 0; e < 4; ++e) {
          float u = v[e];
          u = u > 0.f ? u + 1.f : __expf(u);        // elu(u)+1
          Y[(long)(gr + e) * DM + gc] = f2b(u);
        }
      }
    }
}

// ---- K[ROWS][DM] -> Kt[DM][ROWS]
__global__ __launch_bounds__(256) void k_transpose(const u16* __restrict__ src, u16* __restrict__ dst)
{
  const int t = threadIdx.x;
  const int sx = t & 15, sy = t >> 4;
  const long r0 = (long)blockIdx.x * 128 + sy * 8;
  const long c0 = (long)blockIdx.y * 128 + sx * 8;
  us8 r[8];
#pragma unroll
  for (int v = 0; v < 8; ++v) r[v] = *(const us8*)(src + (r0 + v) * DM + c0);
#pragma unroll
  for (int u = 0; u < 8; ++u) {
    us8 o;
#pragma unroll
    for (int v = 0; v < 8; ++v) o[v] = r[v][u];
    *(us8*)(dst + (c0 + u) * ROWS + r0) = o;
  }
}

// ---- per-chunk K column sums
__global__ __launch_bounds__(256) void k_cksum(const u16* __restrict__ Kp, float* __restrict__ cs)
{
  const int id = blockIdx.x * 256 + threadIdx.x;
  const int i = id & 1023, b = (id >> 10) & 3, j = id >> 12;
  const u16* p = Kp + ((long)j * CR + b) * DM + i;
  float a = 0.f;
#pragma unroll 8
  for (int tl = 0; tl < CHUNK; ++tl) a += b2f(p[(long)tl * BB * DM]);
  cs[id] = a;
}

// ---- z cumsum (fp32 running, bf16 store)
__global__ __launch_bounds__(256) void k_zfill(const u16* __restrict__ Kp,
                                               const float* __restrict__ cs,
                                               u16* __restrict__ z)
{
  const int id = blockIdx.x * 256 + threadIdx.x;
  const int i = id & 1023, b = (id >> 10) & 3, j = id >> 12;
  float a = 0.f;
  for (int j2 = 0; j2 < j; ++j2) a += cs[j2 * 4096 + b * 1024 + i];
  const u16* p = Kp + ((long)j * CR + b) * DM + i;
  u16* q = z + ((long)j * CR + b) * DM + i;
  for (int tl = 0; tl < CHUNK; ++tl) {
    a += b2f(p[(long)tl * BB * DM]);
    q[(long)tl * BB * DM] = f2b(a);
  }
}

// ---- per-chunk G[j][m][i] = sum_{r in chunk} V[r][m] K[r][i].  XCD j-grouped.
__global__ __launch_bounds__(512, 2) void k_gemm_g2(
    const u16* __restrict__ Vt, const u16* __restrict__ Kt, u16* __restrict__ G)
{
  __shared__ __align__(16) u16 sm[65536];
  floatx4 acc[8][4] = {};
  const int id = blockIdx.x;           // 512
  const int x = id & 7, s = id >> 3;   // x = XCD, s = slot on that XCD
  const int j = x + 8 * (s >> 4);      // all 16 blocks of chunk j on XCD x
  const int nm = s & 15;
  const int n0 = (nm & 3) * 256;       // key index i
  const int m0 = (nm >> 2) * 256;      // model index m
  gemm256s(Vt + (long)m0 * ROWS + j * CR, ROWS,
           Kt + (long)n0 * ROWS + j * CR, ROWS, CR,
           Vt, ROWS, Kt, ROWS, 0, sm, sm + 32768, acc);
  const int t = threadIdx.x, w = t >> 6, lane = t & 63;
  const int wm = w >> 2, wn = w & 3, quad = lane >> 4, c16 = lane & 15;
  u16* Gj = G + (long)j * DM * DM;
#pragma unroll
  for (int mi = 0; mi < 8; ++mi)
#pragma unroll
    for (int ni = 0; ni < 4; ++ni) {
      const int gr = m0 + wm * 128 + mi * 16 + quad * 4;
      const int gc = n0 + wn * 64 + ni * 16 + c16;
      floatx4 v = acc[mi][ni];
#pragma unroll
      for (int e = 0; e < 4; ++e) Gj[(long)(gr + e) * DM + gc] = f2b(v[e]);
    }
}

// ---- exclusive prefix over chunks
__global__ __launch_bounds__(256) void k_prefix(u16* __restrict__ G)
{
  const long id = (long)blockIdx.x * 256 + threadIdx.x;
  float a = 0.f;
#pragma unroll
  for (int j = 0; j < NC; ++j) {
    u16* p = G + (long)j * DM * DM + id;
    float g = b2f(*p);
    *p = f2b(a);
    a += g;
  }
}

// ---- intra-chunk scores, masked; upper-triangle blocks skip the GEMM. XCD j-grouped.
__global__ __launch_bounds__(256) void k_scores(
    const u16* __restrict__ Q, const u16* __restrict__ Kp, u16* __restrict__ P)
{
  __shared__ __align__(16) u16 sA[4096];
  __shared__ __align__(16) u16 sB[4096];
  floatx4 acc[4][4] = {};
  const int id = blockIdx.x;           // 512
  const int x = id & 7, s = id >> 3;   // s: 0..63
  const int j = x + 8 * (s >> 4);
  const int nm = s & 15;
  const int n0 = (nm & 3) * 128;
  const int m0 = (nm >> 2) * 128;
  if (n0 <= m0) {   // lower/diagonal blocks only; others fully masked -> zeros
    gemm128(Q + ((long)j * CR + m0) * DM, DM,
            Kp + ((long)j * CR + n0) * DM, DM, DM, sA, sB, acc);
  }
  const int t = threadIdx.x, lane = t & 63, w = t >> 6;
  const int wm = w >> 1, wn = w & 1, quad = lane >> 4, c16 = lane & 15;
  u16* Pj = P + (long)j * CR * CR;
#pragma unroll
  for (int im = 0; im < 4; ++im)
#pragma unroll
    for (int in = 0; in < 4; ++in) {
      const int gc = n0 + wn * 64 + in * 16 + c16;
      const int gr = m0 + wm * 64 + im * 16 + quad * 4;
      const bool valid = (gc <= gr + 3);
      floatx4 v = acc[im][in];
#pragma unroll
      for (int e = 0; e < 4; ++e)
        Pj[(long)(gr + e) * CR + gc] = valid ? f2b(v[e]) : (u16)0;
    }
}

// ---- denom[row] = q_row . z_row
__global__ __launch_bounds__(256) void k_denom(
    const u16* __restrict__ Q, const u16* __restrict__ z, float* __restrict__ denom)
{
  const int w = threadIdx.x >> 6, lane = threadIdx.x & 63;
  const long row = (long)blockIdx.x * 4 + w;
  const u16* q = Q + row * DM;
  const u16* zz = z + row * DM;
  float s = 0.f;
#pragma unroll
  for (int p = 0; p < 2; ++p) {
    const int off = lane * 8 + p * 512;
    us8 q8 = *(const us8*)(q + off);
    us8 z8 = *(const us8*)(zz + off);
#pragma unroll
    for (int e = 0; e < 8; ++e) s += b2f(q8[e]) * b2f(z8[e]);
  }
#pragma unroll
  for (int d = 32; d > 0; d >>= 1) s += __shfl_down(s, d, 64);
  if (lane == 0) denom[row] = s;
}

// ---- y = (P @ V + Q @ S_chunkstart) / denom. 256x256 tiles, fused emit,
//      XCD j-grouped. SINGLE two-segment pipelined GEMM: segment1 = PV with K
//      truncated to m0+256 (P cols beyond are masked zeros), segment2 = Q@St.
__global__ __launch_bounds__(512, 2) void k_out2(
    const u16* __restrict__ P, const u16* __restrict__ Vt,
    const u16* __restrict__ Q, const u16* __restrict__ St,
    const float* __restrict__ denom, void* __restrict__ out,
    const int* __restrict__ flag)
{
  __shared__ __align__(16) u16 sm[65536];
  floatx4 acc[8][4] = {};
  const int id = blockIdx.x;           // 256
  const int x = id & 7, s = id >> 3;   // s: 0..31
  const int j = x + 8 * (s >> 3);      // 8 blocks of chunk j contiguous on XCD x
  const int nm = s & 7;
  const int n0 = (nm & 3) * 256;       // model col
  const int m0 = (nm >> 2) * 256;      // row in chunk
  gemm256s(P + (long)j * CR * CR + (long)m0 * CR, CR,
           Vt + (long)n0 * ROWS + j * CR, ROWS, m0 + 256,
           Q + ((long)j * CR + m0) * DM, DM,
           St + (long)j * DM * DM + (long)n0 * DM, DM, DM,
           sm, sm + 32768, acc);
  const int t = threadIdx.x, w = t >> 6, lane = t & 63;
  const int wm = w >> 2, wn = w & 3, quad = lane >> 4, c16 = lane & 15;
  const int isf16 = *flag;
  float* of = (float*)out;
  u16* ob = (u16*)out;
#pragma unroll
  for (int mi = 0; mi < 8; ++mi)
#pragma unroll
    for (int ni = 0; ni < 4; ++ni) {
      const int gc = n0 + wn * 64 + ni * 16 + c16;
      const int grl = m0 + wm * 128 + mi * 16 + quad * 4;
      const long gr = (long)j * CR + grl;
      floatx4 v = acc[mi][ni];
#pragma unroll
      for (int e = 0; e < 4; ++e) {
        const float d = denom[gr + e];
        const float y = v[e] / d;
        if (isf16) ob[(gr + e) * DM + gc] = f2b(y);
        else       of[(gr + e) * DM + gc] = y;
      }
    }
}

extern "C" void kernel_launch(void* const* d_in, const int* in_sizes, int n_in,
                              void* d_out, int out_size, void* d_ws, size_t ws_size,
                              hipStream_t stream)
{
  char* ws = (char*)d_ws;
  u16*  xc  = (u16*)(ws);              // region A [32M]: xc, later z
  u16*  z   = (u16*)(ws);
  u16*  Q   = (u16*)(ws + 32 * MB);    // region B [32M]
  u16*  K   = (u16*)(ws + 64 * MB);    // region C [32M]
  u16*  Kt  = (u16*)(ws + 96 * MB);    // region D [32M]: Kt, later P (16M)
  u16*  P   = (u16*)(ws + 96 * MB);
  u16*  Vt  = (u16*)(ws + 128 * MB);   // region E [32M]
  u16*  G   = (u16*)(ws + 160 * MB);   // region F [64M] (St after k_prefix)
  u16*  Wqc = (u16*)(ws + 224 * MB);
  u16*  Wkc = (u16*)(ws + 226 * MB);
  u16*  Wvc = (u16*)(ws + 228 * MB);
  float* cs = (float*)(ws + 230 * MB);
  float* dn = (float*)(ws + 230 * MB + 524288);
  int* flag = (int*)(ws + 230 * MB + 524288 + 65536);

  dim3 blk(256), blk5(512);
  k_sniff<<<1, 64, 0, stream>>>((const u16*)d_in[0], flag);
  k_convert<<<16384, blk, 0, stream>>>(d_in[0], xc, flag, (long)ROWS * DM);
  k_convert<<<1024, blk, 0, stream>>>(d_in[1], Wqc, flag, (long)DM * DM);
  k_convert<<<1024, blk, 0, stream>>>(d_in[2], Wkc, flag, (long)DM * DM);
  k_convert<<<1024, blk, 0, stream>>>(d_in[3], Wvc, flag, (long)DM * DM);
  k_proj2<<<dim3(256), blk5, 0, stream>>>(xc, Wqc, Q, 1);
  k_proj2<<<dim3(256), blk5, 0, stream>>>(xc, Wkc, K, 1);
  k_proj2<<<dim3(256), blk5, 0, stream>>>(xc, Wvc, Vt, 2);
  k_transpose<<<dim3(128, 8), blk, 0, stream>>>(K, Kt);
  k_cksum<<<dim3(512), blk, 0, stream>>>(K, cs);
  k_zfill<<<dim3(512), blk, 0, stream>>>(K, cs, z);       // z overlays dead xc
  k_gemm_g2<<<dim3(512), blk5, 0, stream>>>(Vt, Kt, G);
  k_prefix<<<dim3(4096), blk, 0, stream>>>(G);
  k_scores<<<dim3(512), blk, 0, stream>>>(Q, K, P);       // P overlays dead Kt
  k_denom<<<dim3(4096), blk, 0, stream>>>(Q, z, dn);
  k_out2<<<dim3(256), blk5, 0, stream>>>(P, Vt, Q, G, dn, d_out, flag);
}